// Round 11
// baseline (1298.202 us; speedup 1.0000x reference)
//
#include <hip/hip_runtime.h>
#include <cstdint>
#include <cstring>
#include <cmath>

constexpr int kH    = 16;
constexpr int kL    = 24;
constexpr int kS    = 4096;
constexpr int kEOS  = 129;
constexpr float kSCALE = 0.125f;   // 1/sqrt(64)
constexpr int kNS   = 64;          // attention splits (deepened for TLP)
constexpr int kTOK  = kS / kNS;    // 64 tokens per split

struct G10 { float g[10]; };

// ---------------- reduction helpers ----------------

__device__ __forceinline__ float wave_sum(float v) {
  v += __shfl_xor(v, 32, 64); v += __shfl_xor(v, 16, 64);
  v += __shfl_xor(v, 8, 64);  v += __shfl_xor(v, 4, 64);
  v += __shfl_xor(v, 2, 64);  v += __shfl_xor(v, 1, 64);
  return v;
}
__device__ __forceinline__ float wave_max(float v) {
  v = fmaxf(v, __shfl_xor(v, 32, 64)); v = fmaxf(v, __shfl_xor(v, 16, 64));
  v = fmaxf(v, __shfl_xor(v, 8, 64));  v = fmaxf(v, __shfl_xor(v, 4, 64));
  v = fmaxf(v, __shfl_xor(v, 2, 64));  v = fmaxf(v, __shfl_xor(v, 1, 64));
  return v;
}
__device__ __forceinline__ float block_sum4(float v, float* red) {
  v = wave_sum(v);
  if ((threadIdx.x & 63) == 0) red[threadIdx.x >> 6] = v;
  __syncthreads();
  float s = red[0] + red[1] + red[2] + red[3];
  __syncthreads();
  return s;
}
__device__ __forceinline__ float block_max4(float v, float* red) {
  v = wave_max(v);
  if ((threadIdx.x & 63) == 0) red[threadIdx.x >> 6] = v;
  __syncthreads();
  float s = fmaxf(fmaxf(red[0], red[1]), fmaxf(red[2], red[3]));
  __syncthreads();
  return s;
}

__device__ __forceinline__ void ln_stats(const float* __restrict__ h, float* red,
                                         float& mean, float& rs) {
  int tid = threadIdx.x;
  float v0 = h[tid], v1 = h[tid + 256], v2 = h[tid + 512], v3 = h[tid + 768];
  float s = block_sum4(v0 + v1 + v2 + v3, red);
  mean = s * (1.0f / 1024.0f);
  float d0 = v0 - mean, d1 = v1 - mean, d2 = v2 - mean, d3 = v3 - mean;
  float sq = block_sum4(d0 * d0 + d1 * d1 + d2 * d2 + d3 * d3, red);
  rs = 1.0f / sqrtf(sq * (1.0f / 1024.0f) + 1e-5f);
}

__device__ __forceinline__ float gelu_f(float x) {
  float t = tanhf(0.7978845608028654f * (x + 0.044715f * x * x * x));
  return 0.5f * x * (1.0f + t);
}

// wave-parallel top-10 + gumbel sampler. Whole block must call (internal sync).
__device__ int wave_sampler(const float* __restrict__ logits, int n3,
                            const float* __restrict__ gb, bool eosmode,
                            int* ish) {
  int tid = threadIdx.x;
  if (tid < 64) {
    float a0 = (tid < n3) ? logits[tid] : -1e30f;
    float a1 = (tid + 64 < n3) ? logits[tid + 64] : -1e30f;
    float a2 = (tid + 128 < n3) ? logits[tid + 128] : -1e30f;
    float m = wave_max(fmaxf(a0, fmaxf(a1, a2)));
    float p0 = expf(a0 - m), p1 = expf(a1 - m), p2 = expf(a2 - m);
    float s = wave_sum(p0 + p1 + p2);
    p0 = p0 / s; p1 = p1 / s; p2 = p2 / s;
    float tp[10]; int ti[10];
    #pragma unroll
    for (int k = 0; k < 10; ++k) {
      float bv = p0; int bi = tid;
      if (p1 > bv) { bv = p1; bi = tid + 64; }
      if (p2 > bv) { bv = p2; bi = tid + 128; }
      #pragma unroll
      for (int off = 32; off > 0; off >>= 1) {
        float ov = __shfl_xor(bv, off, 64);
        int   oi = __shfl_xor(bi, off, 64);
        if (ov > bv || (ov == bv && oi < bi)) { bv = ov; bi = oi; }
      }
      tp[k] = bv; ti[k] = bi;
      if (bi == tid) p0 = -2.f;
      else if (bi == tid + 64) p1 = -2.f;
      else if (bi == tid + 128) p2 = -2.f;
    }
    if (tid == 0) {
      int choice;
      if (eosmode) {
        int is_eos = (ti[0] == kEOS);
        float mp[10]; float msum = 0.f;
        for (int k = 0; k < 10; ++k) {
          mp[k] = tp[k] * ((ti[k] != kEOS) ? 1.f : 0.f);
          msum += mp[k];
        }
        float bestsc = -1e30f; int ba = 0;
        for (int k = 0; k < 10; ++k) {
          float sc = logf(mp[k] / msum + 1e-9f) + gb[k];
          if (sc > bestsc) { bestsc = sc; ba = k; }
        }
        choice = is_eos ? kEOS : ti[ba];
      } else {
        float bestsc = -1e30f; int ba = 0;
        for (int k = 0; k < 10; ++k) {
          float sc = logf(tp[k] + 1e-9f) + gb[k];
          if (sc > bestsc) { bestsc = sc; ba = k; }
        }
        choice = ti[ba];
      }
      *ish = choice;
    }
  }
  __syncthreads();
  return *ish;
}

// ---------------- layer kernels ----------------

// A: fused LN1 + QKV gemv -> qkv_part[16][3072]; grid (48,16), 16-quad cols.
__global__ __launch_bounds__(256) void k_ln_qkv(const float* __restrict__ h,
                                                const float* __restrict__ g,
                                                const float* __restrict__ Wq,
                                                const float* __restrict__ Wk,
                                                const float* __restrict__ Wv,
                                                float* __restrict__ qkv_part,
                                                float* __restrict__ hres) {
  __shared__ float red4[4];
  __shared__ float xs[64];
  __shared__ float4 sh4[256];
  int tid = threadIdx.x;
  float mean, rs;
  ln_stats(h, red4, mean, rs);
  int by = blockIdx.y, rb = by * 64;
  if (tid < 64) xs[tid] = (h[rb + tid] - mean) * rs * g[rb + tid];
  if (blockIdx.x == 0 && tid < 64) hres[rb + tid] = h[rb + tid];
  __syncthreads();
  int c4 = tid & 15, w = tid >> 4;
  int vcol4 = blockIdx.x * 16 + c4;          // 0..767 (3072 cols)
  int mat = vcol4 >> 8;
  const float* W = (mat == 0) ? Wq : ((mat == 1) ? Wk : Wv);
  const float4* W4 = reinterpret_cast<const float4*>(W);
  int wcol4 = vcol4 & 255;
  float4 acc = {0.f, 0.f, 0.f, 0.f};
  int r0 = w * 4;
  #pragma unroll
  for (int i = 0; i < 4; ++i) {
    int j = r0 + i;
    float xv = xs[j];
    float4 wv = W4[(size_t)(rb + j) * 256 + wcol4];
    acc.x += xv * wv.x; acc.y += xv * wv.y; acc.z += xv * wv.z; acc.w += xv * wv.w;
  }
  sh4[tid] = acc;
  __syncthreads();
  if (tid < 16) {
    float4 a = sh4[tid];
    #pragma unroll
    for (int k = 1; k < 16; ++k) {
      float4 b = sh4[k * 16 + tid];
      a.x += b.x; a.y += b.y; a.z += b.z; a.w += b.w;
    }
    reinterpret_cast<float4*>(qkv_part)[(size_t)by * 768 + blockIdx.x * 16 + tid] = a;
  }
}

// B: attention partials. grid (kNS=64, kH) = 1024 blocks (4/CU).
//    V prefetched to registers before softmax. part stride 68: [m,l,-,-,o[64]]
__global__ __launch_bounds__(256) void k_attn(const float* __restrict__ qkv_part,
                                              const float* __restrict__ Kc,
                                              const float* __restrict__ Vc,
                                              float* __restrict__ part) {
  __shared__ float4 q4[16];
  __shared__ float4 kn4[16];
  __shared__ float4 vn4[16];
  __shared__ float sc[68];
  __shared__ float red4[4];
  __shared__ float4 ored[16][17];
  int split = blockIdx.x, head = blockIdx.y;
  int tid = threadIdx.x;
  if (tid < 64) {
    float s = 0.f;
    #pragma unroll
    for (int p = 0; p < 16; ++p) s += qkv_part[p * 3072 + head * 64 + tid];
    ((float*)q4)[tid] = s;
  } else if (tid < 128) {
    int d = tid - 64; float s = 0.f;
    #pragma unroll
    for (int p = 0; p < 16; ++p) s += qkv_part[p * 3072 + 1024 + head * 64 + d];
    ((float*)kn4)[d] = s;
  } else if (tid < 192) {
    int d = tid - 128; float s = 0.f;
    #pragma unroll
    for (int p = 0; p < 16; ++p) s += qkv_part[p * 3072 + 2048 + head * 64 + d];
    ((float*)vn4)[d] = s;
  }
  __syncthreads();
  int base = split * kTOK;
  bool last = (split == kNS - 1);
  int count = kTOK + (last ? 1 : 0);
  int wv = tid >> 6, lane = tid & 63, grp = lane >> 4, l16 = lane & 15;
  int g0 = wv * 4 + grp;                     // 16 token-groups, 4 tokens each
  float4 qf = q4[l16];
  const float4* K4 = reinterpret_cast<const float4*>(Kc);
  const float4* V4 = reinterpret_cast<const float4*>(Vc);
  #pragma unroll
  for (int i = 0; i < 4; ++i) {
    int t = g0 + 16 * i;
    float4 kf = K4[(size_t)(base + t) * 256 + head * 16 + l16];
    float d = qf.x * kf.x + qf.y * kf.y + qf.z * kf.z + qf.w * kf.w;
    d += __shfl_xor(d, 1, 16); d += __shfl_xor(d, 2, 16);
    d += __shfl_xor(d, 4, 16); d += __shfl_xor(d, 8, 16);
    if (l16 == 0) sc[t] = d * kSCALE;
  }
  if (last && g0 == 0) {
    float4 kf = kn4[l16];
    float d = qf.x * kf.x + qf.y * kf.y + qf.z * kf.z + qf.w * kf.w;
    d += __shfl_xor(d, 1, 16); d += __shfl_xor(d, 2, 16);
    d += __shfl_xor(d, 4, 16); d += __shfl_xor(d, 8, 16);
    if (l16 == 0) sc[64] = d * kSCALE;
  }
  // V prefetch into registers — in flight across the softmax barriers
  float4 vreg[4];
  #pragma unroll
  for (int i = 0; i < 4; ++i) {
    int t = g0 + 16 * i;
    vreg[i] = V4[(size_t)(base + t) * 256 + head * 16 + l16];
  }
  __syncthreads();
  float v = (tid < count) ? sc[tid] : -1e30f;
  float m = block_max4(v, red4);
  float pexp = 0.f;
  if (tid < count) { pexp = expf(sc[tid] - m); sc[tid] = pexp; }
  float l = block_sum4(pexp, red4);
  float4 acc = {0.f, 0.f, 0.f, 0.f};
  #pragma unroll
  for (int i = 0; i < 4; ++i) {
    int t = g0 + 16 * i;
    float p = sc[t];
    acc.x += p * vreg[i].x; acc.y += p * vreg[i].y;
    acc.z += p * vreg[i].z; acc.w += p * vreg[i].w;
  }
  if (last && g0 == 0) {
    float p = sc[64];
    float4 vf = vn4[l16];
    acc.x += p * vf.x; acc.y += p * vf.y; acc.z += p * vf.z; acc.w += p * vf.w;
  }
  ored[g0][l16] = acc;
  __syncthreads();
  float* pp = &part[(size_t)(head * kNS + split) * 68];
  if (tid < 16) {
    float4 s = ored[0][tid];
    #pragma unroll
    for (int k = 1; k < 16; ++k) {
      float4 b = ored[k][tid];
      s.x += b.x; s.y += b.y; s.z += b.z; s.w += b.w;
    }
    reinterpret_cast<float4*>(pp + 4)[tid] = s;
  }
  if (tid == 0) { pp[0] = m; pp[1] = l; }
}

// C: combine 64 splits per head + Wo gemv (8-quad colblocks, grid (32,16)=512)
__global__ __launch_bounds__(256) void k_comb_wo(const float* __restrict__ part,
                                                 const float* __restrict__ Wo,
                                                 float* __restrict__ hout) {
  __shared__ float o[64];
  __shared__ float4 sh4[256];
  int tid = threadIdx.x;
  int head = blockIdx.y, bx = blockIdx.x;
  if (tid < 64) {
    const float* pp = part + (size_t)(head * kNS) * 68;
    float m = -1e30f;
    for (int s = 0; s < kNS; ++s) m = fmaxf(m, pp[s * 68]);
    float l = 0.f, acc = 0.f;
    for (int s = 0; s < kNS; ++s) {
      float e = expf(pp[s * 68] - m);
      l += e * pp[s * 68 + 1];
      acc += e * pp[s * 68 + 4 + tid];
    }
    o[tid] = acc / l;
  }
  __syncthreads();
  int c4 = tid & 7, w = tid >> 3;            // 8 quads, 32 row-groups of 2
  int vcol4 = bx * 8 + c4;
  const float4* W4 = reinterpret_cast<const float4*>(Wo);
  float4 acc = {0.f, 0.f, 0.f, 0.f};
  int r0 = w * 2;
  #pragma unroll
  for (int i = 0; i < 2; ++i) {
    int r = r0 + i;
    float xv = o[r];
    float4 wv = W4[(size_t)(head * 64 + r) * 256 + vcol4];
    acc.x += xv * wv.x; acc.y += xv * wv.y; acc.z += xv * wv.z; acc.w += xv * wv.w;
  }
  sh4[tid] = acc;
  __syncthreads();
  if (tid < 8) {
    float4 a = sh4[tid];
    #pragma unroll
    for (int k = 1; k < 32; ++k) {
      float4 b = sh4[k * 8 + tid];
      a.x += b.x; a.y += b.y; a.z += b.z; a.w += b.w;
    }
    int vcol = (bx * 8 + tid) * 4;
    atomicAdd(&hout[vcol],     a.x);
    atomicAdd(&hout[vcol + 1], a.y);
    atomicAdd(&hout[vcol + 2], a.z);
    atomicAdd(&hout[vcol + 3], a.w);
  }
}

// D: fused LN2 + [Wg|Wu] gemv -> gu_part[16][8192]; bx==0 copies h -> hres
__global__ __launch_bounds__(256) void k_ln_gu(const float* __restrict__ h,
                                               const float* __restrict__ g,
                                               const float* __restrict__ Wg,
                                               const float* __restrict__ Wu,
                                               float* __restrict__ gu_part,
                                               float* __restrict__ hres) {
  __shared__ float red4[4];
  __shared__ float xs[64];
  __shared__ float4 sh4[256];
  int tid = threadIdx.x;
  float mean, rs;
  ln_stats(h, red4, mean, rs);
  int by = blockIdx.y, rb = by * 64;
  if (tid < 64) xs[tid] = (h[rb + tid] - mean) * rs * g[rb + tid];
  if (blockIdx.x == 0 && tid < 64) hres[rb + tid] = h[rb + tid];
  __syncthreads();
  int c4 = tid & 63, w = tid >> 6;
  int vcol4 = blockIdx.x * 64 + c4;          // 0..2047 (8192 cols)
  int mat = vcol4 >> 10;
  const float4* W4 = reinterpret_cast<const float4*>(mat ? Wu : Wg);
  int wcol4 = vcol4 & 1023;
  float4 acc = {0.f, 0.f, 0.f, 0.f};
  int r0 = w * 16;
  #pragma unroll
  for (int i = 0; i < 16; ++i) {
    int j = r0 + i;
    float xv = xs[j];
    float4 wv = W4[(size_t)(rb + j) * 1024 + wcol4];
    acc.x += xv * wv.x; acc.y += xv * wv.y; acc.z += xv * wv.z; acc.w += xv * wv.w;
  }
  sh4[tid] = acc;
  __syncthreads();
  if (tid < 64) {
    float4 a = sh4[tid], b = sh4[tid + 64], c = sh4[tid + 128], d = sh4[tid + 192];
    a.x += b.x + c.x + d.x; a.y += b.y + c.y + d.y;
    a.z += b.z + c.z + d.z; a.w += b.w + c.w + d.w;
    reinterpret_cast<float4*>(gu_part)[(size_t)by * 2048 + blockIdx.x * 64 + tid] = a;
  }
}

// E: act = gelu(sum g)*sum u, then act @ Wd; grid (8,64)=512, 32-quad cols
__global__ __launch_bounds__(256) void k_act_wd(const float* __restrict__ gu_part,
                                                const float* __restrict__ Wd,
                                                float* __restrict__ hout) {
  __shared__ float xs[64];
  __shared__ float4 sh4[256];
  int tid = threadIdx.x;
  int by = blockIdx.y, rb = by * 64;
  if (tid < 64) {
    float gs = 0.f, us = 0.f;
    #pragma unroll
    for (int p = 0; p < 16; ++p) {
      gs += gu_part[p * 8192 + rb + tid];
      us += gu_part[p * 8192 + 4096 + rb + tid];
    }
    xs[tid] = gelu_f(gs) * us;
  }
  __syncthreads();
  int c4 = tid & 31, w = tid >> 5;           // 32 quads, 8 row-groups of 8
  int vcol4 = blockIdx.x * 32 + c4;          // 0..255
  const float4* W4 = reinterpret_cast<const float4*>(Wd);
  float4 acc = {0.f, 0.f, 0.f, 0.f};
  int r0 = w * 8;
  #pragma unroll
  for (int i = 0; i < 8; ++i) {
    int j = r0 + i;
    float xv = xs[j];
    float4 wv = W4[(size_t)(rb + j) * 256 + vcol4];
    acc.x += xv * wv.x; acc.y += xv * wv.y; acc.z += xv * wv.z; acc.w += xv * wv.w;
  }
  sh4[tid] = acc;
  __syncthreads();
  if (tid < 32) {
    float4 a = sh4[tid];
    #pragma unroll
    for (int k = 1; k < 8; ++k) {
      float4 b = sh4[k * 32 + tid];
      a.x += b.x; a.y += b.y; a.z += b.z; a.w += b.w;
    }
    int vcol = (blockIdx.x * 32 + tid) * 4;
    atomicAdd(&hout[vcol],     a.x);
    atomicAdd(&hout[vcol + 1], a.y);
    atomicAdd(&hout[vcol + 2], a.z);
    atomicAdd(&hout[vcol + 3], a.w);
  }
}

// ---------------- head kernels ----------------

// g1: 8-quad colblocks, grid (32, ny). Rows r<1024 inline LNf(hA);
//     [1024,2048) gather c1emb[z]; >=2048 gather c2emb[y] (wave-sampled locally).
__global__ __launch_bounds__(256) void k_head_g1(const float* __restrict__ hA,
                                                 const float* __restrict__ lnfg,
                                                 const float* __restrict__ c1emb,
                                                 const float* __restrict__ c2emb,
                                                 const float* __restrict__ zlogits,
                                                 const float* __restrict__ ylogits,
                                                 G10 Gz, G10 Gy,
                                                 const float* __restrict__ W,
                                                 float* __restrict__ t1_part,
                                                 const float* __restrict__ b3,
                                                 float* __restrict__ logits, int n3,
                                                 float* __restrict__ outz,
                                                 float* __restrict__ outy) {
  __shared__ float red4[4];
  __shared__ float xs[64];
  __shared__ float4 sh4[256];
  __shared__ int ish;
  int tid = threadIdx.x;
  int by = blockIdx.y, rb = by * 64;
  int zv = 0, yv = 0;
  if (by >= 16 && by < 32) {
    zv = wave_sampler(zlogits, 130, Gz.g, true, &ish);
    if (outz && blockIdx.x == 0 && by == 16 && tid == 0) *outz = (float)zv;
  } else if (by >= 32) {
    yv = wave_sampler(ylogits, 128, Gy.g, false, &ish);
    if (outy && blockIdx.x == 0 && by == 32 && tid == 0) *outy = (float)yv;
  }
  float mean, rs;
  ln_stats(hA, red4, mean, rs);
  if (blockIdx.x == 0 && by == 0 && tid < n3) logits[tid] = b3[tid];
  if (tid < 64) {
    int r = rb + tid;
    if (r < 1024) {
      xs[tid] = (hA[r] - mean) * rs * lnfg[r];
    } else if (r < 2048) {
      int zi = zv > 127 ? 127 : zv;
      xs[tid] = c1emb[(size_t)zi * 1024 + (r - 1024)];
    } else {
      xs[tid] = c2emb[(size_t)yv * 1024 + (r - 2048)];
    }
  }
  __syncthreads();
  int c4 = tid & 7, w = tid >> 3;
  int vcol4 = blockIdx.x * 8 + c4;
  const float4* W4 = reinterpret_cast<const float4*>(W);
  float4 acc = {0.f, 0.f, 0.f, 0.f};
  int r0 = w * 2;
  #pragma unroll
  for (int i = 0; i < 2; ++i) {
    float xv = xs[r0 + i];
    float4 wv = W4[(size_t)(rb + r0 + i) * 256 + vcol4];
    acc.x += xv * wv.x; acc.y += xv * wv.y; acc.z += xv * wv.z; acc.w += xv * wv.w;
  }
  sh4[tid] = acc;
  __syncthreads();
  if (tid < 8) {
    float4 a = sh4[tid];
    #pragma unroll
    for (int k = 1; k < 32; ++k) {
      float4 b = sh4[k * 8 + tid];
      a.x += b.x; a.y += b.y; a.z += b.z; a.w += b.w;
    }
    reinterpret_cast<float4*>(t1_part)[(size_t)by * 256 + blockIdx.x * 8 + tid] = a;
  }
}

// g2: relu(b1 + sum_ny t1_part) @ W; 8-quad colblocks, grid (32, 16)
__global__ __launch_bounds__(256) void k_head_g2(const float* __restrict__ t1_part,
                                                 int ny,
                                                 const float* __restrict__ b1,
                                                 const float* __restrict__ W,
                                                 float* __restrict__ t2_part) {
  __shared__ float xs[64];
  __shared__ float4 sh4[256];
  int tid = threadIdx.x;
  int by = blockIdx.y, rb = by * 64;
  if (tid < 64) {
    float s = b1[rb + tid];
    for (int p = 0; p < ny; ++p) s += t1_part[p * 1024 + rb + tid];
    xs[tid] = fmaxf(s, 0.f);
  }
  __syncthreads();
  int c4 = tid & 7, w = tid >> 3;
  int vcol4 = blockIdx.x * 8 + c4;
  const float4* W4 = reinterpret_cast<const float4*>(W);
  float4 acc = {0.f, 0.f, 0.f, 0.f};
  int r0 = w * 2;
  #pragma unroll
  for (int i = 0; i < 2; ++i) {
    float xv = xs[r0 + i];
    float4 wv = W4[(size_t)(rb + r0 + i) * 256 + vcol4];
    acc.x += xv * wv.x; acc.y += xv * wv.y; acc.z += xv * wv.z; acc.w += xv * wv.w;
  }
  sh4[tid] = acc;
  __syncthreads();
  if (tid < 8) {
    float4 a = sh4[tid];
    #pragma unroll
    for (int k = 1; k < 32; ++k) {
      float4 b = sh4[k * 8 + tid];
      a.x += b.x; a.y += b.y; a.z += b.z; a.w += b.w;
    }
    reinterpret_cast<float4*>(t2_part)[(size_t)by * 256 + blockIdx.x * 8 + tid] = a;
  }
}

// g3: relu(b2 + sum_16 t2_part) @ W (1024 x n3) -> atomicAdd logits
__global__ __launch_bounds__(256) void k_head_g3(const float* __restrict__ t2_part,
                                                 const float* __restrict__ b2,
                                                 const float* __restrict__ W,
                                                 float* __restrict__ logits, int n3) {
  __shared__ float xs[64];
  int tid = threadIdx.x;
  int rb = blockIdx.x * 64;
  if (tid < 64) {
    float s = b2[rb + tid];
    #pragma unroll
    for (int p = 0; p < 16; ++p) s += t2_part[p * 1024 + rb + tid];
    xs[tid] = fmaxf(s, 0.f);
  }
  __syncthreads();
  if (tid < n3) {
    float acc = 0.f;
    for (int i = 0; i < 64; ++i) acc += xs[i] * W[(size_t)(rb + i) * n3 + tid];
    atomicAdd(&logits[tid], acc);
  }
}

// final sampler (stage 3, x coordinate)
__global__ void k_sample_final(const float* __restrict__ logits,
                               float* __restrict__ outslot, G10 gb) {
  __shared__ int ish;
  int v = wave_sampler(logits, 128, gb.g, false, &ish);
  if (threadIdx.x == 0) *outslot = (float)v;
}

// ---------------- host: JAX threefry2x32 (partitionable) ----------------

static inline uint32_t rotl32(uint32_t x, uint32_t r) { return (x << r) | (x >> (32 - r)); }

static void threefry2x32(uint32_t k0, uint32_t k1, uint32_t x0, uint32_t x1,
                         uint32_t* o0, uint32_t* o1) {
  uint32_t ks0 = k0, ks1 = k1, ks2 = k0 ^ k1 ^ 0x1BD11BDAu;
  const uint32_t R0[4] = {13, 15, 26, 6};
  const uint32_t R1[4] = {17, 29, 16, 24};
  x0 += ks0; x1 += ks1;
  for (int j = 0; j < 4; ++j) { x0 += x1; x1 = rotl32(x1, R0[j]); x1 ^= x0; }
  x0 += ks1; x1 += ks2 + 1u;
  for (int j = 0; j < 4; ++j) { x0 += x1; x1 = rotl32(x1, R1[j]); x1 ^= x0; }
  x0 += ks2; x1 += ks0 + 2u;
  for (int j = 0; j < 4; ++j) { x0 += x1; x1 = rotl32(x1, R0[j]); x1 ^= x0; }
  x0 += ks0; x1 += ks1 + 3u;
  for (int j = 0; j < 4; ++j) { x0 += x1; x1 = rotl32(x1, R1[j]); x1 ^= x0; }
  x0 += ks1; x1 += ks2 + 4u;
  for (int j = 0; j < 4; ++j) { x0 += x1; x1 = rotl32(x1, R0[j]); x1 ^= x0; }
  x0 += ks2; x1 += ks0 + 5u;
  *o0 = x0; *o1 = x1;
}

static void gumbel10_part(uint32_t k0, uint32_t k1, float* g) {
  const float tiny = 1.1754943508222875e-38f;
  for (int i = 0; i < 10; ++i) {
    uint32_t a, c;
    threefry2x32(k0, k1, 0u, (uint32_t)i, &a, &c);
    uint32_t bits = a ^ c;
    uint32_t fb = (bits >> 9) | 0x3f800000u;
    float f; memcpy(&f, &fb, 4);
    f -= 1.0f;
    float u = f * (1.0f - tiny) + tiny;
    if (u < tiny) u = tiny;
    g[i] = -logf(-logf(u));
  }
}

// ---------------- entry ----------------

extern "C" void kernel_launch(void* const* d_in, const int* in_sizes, int n_in,
                              void* d_out, int out_size, void* d_ws, size_t ws_size,
                              hipStream_t stream) {
  (void)in_sizes; (void)n_in; (void)out_size; (void)ws_size;
  const float* x      = (const float*)d_in[0];
  const float* kcache = (const float*)d_in[1];
  const float* vcache = (const float*)d_in[2];
  const float* ln1g   = (const float*)d_in[3];
  const float* Wq     = (const float*)d_in[4];
  const float* Wk     = (const float*)d_in[5];
  const float* Wv     = (const float*)d_in[6];
  const float* Wo     = (const float*)d_in[7];
  const float* ln2g   = (const float*)d_in[8];
  const float* Wg     = (const float*)d_in[9];
  const float* Wu     = (const float*)d_in[10];
  const float* Wd     = (const float*)d_in[11];
  const float* lnfg   = (const float*)d_in[12];
  const float* h1w1 = (const float*)d_in[13]; const float* h1b1 = (const float*)d_in[14];
  const float* h1w2 = (const float*)d_in[15]; const float* h1b2 = (const float*)d_in[16];
  const float* h1w3 = (const float*)d_in[17]; const float* h1b3 = (const float*)d_in[18];
  const float* h2w1 = (const float*)d_in[19]; const float* h2b1 = (const float*)d_in[20];
  const float* h2w2 = (const float*)d_in[21]; const float* h2b2 = (const float*)d_in[22];
  const float* h2w3 = (const float*)d_in[23]; const float* h2b3 = (const float*)d_in[24];
  const float* h3w1 = (const float*)d_in[25]; const float* h3b1 = (const float*)d_in[26];
  const float* h3w2 = (const float*)d_in[27]; const float* h3b2 = (const float*)d_in[28];
  const float* h3w3 = (const float*)d_in[29]; const float* h3b3 = (const float*)d_in[30];
  const float* c1emb = (const float*)d_in[31];
  const float* c2emb = (const float*)d_in[32];

  float* ws = (float*)d_ws;
  float* hA   = ws;                  // 1024
  float* hB   = ws + 1024;           // 1024
  float* qkvp = ws + 2048;           // 16*3072 = 49152
  float* part = ws + 51200;          // 16*64*68 = 69632
  float* gup  = ws + 120832;         // 16*8192 = 131072
  float* t2p  = ws + 251904;         // 16*1024 = 16384
  float* t1p  = gup;                 // reuse (heads only): up to 48*1024
  float* out  = (float*)d_out;

  for (int l = 0; l < kL; ++l) {
    const float* Wq_l = Wq + (size_t)l * 1024 * 1024;
    const float* Wk_l = Wk + (size_t)l * 1024 * 1024;
    const float* Wv_l = Wv + (size_t)l * 1024 * 1024;
    const float* Wo_l = Wo + (size_t)l * 1024 * 1024;
    const float* Wg_l = Wg + (size_t)l * 1024 * 4096;
    const float* Wu_l = Wu + (size_t)l * 1024 * 4096;
    const float* Wd_l = Wd + (size_t)l * 4096 * 1024;
    const float* Kc_l = kcache + (size_t)l * kS * 1024;
    const float* Vc_l = vcache + (size_t)l * kS * 1024;
    const float* h_in = (l == 0) ? x : hA;

    // A: LN1 fused + QKV partials (768 blocks); copies h_in -> hB
    k_ln_qkv<<<dim3(48, 16), 256, 0, stream>>>(h_in, ln1g + (size_t)l * 1024,
                                               Wq_l, Wk_l, Wv_l, qkvp, hB);
    // B: attention partials over S+1 (1024 blocks, V reg-prefetched)
    k_attn<<<dim3(kNS, kH), 256, 0, stream>>>(qkvp, Kc_l, Vc_l, part);
    // C: combine + Wo, hB += o @ Wo (512 blocks)
    k_comb_wo<<<dim3(32, kH), 256, 0, stream>>>(part, Wo_l, hB);
    // D: LN2 fused + [Wg|Wu] partials (512 blocks); copies hB -> hA
    k_ln_gu<<<dim3(32, 16), 256, 0, stream>>>(hB, ln2g + (size_t)l * 1024,
                                              Wg_l, Wu_l, gup, hA);
    // E: hA += (gelu(g)*u) @ Wd (512 blocks)
    k_act_wd<<<dim3(8, 64), 256, 0, stream>>>(gup, Wd_l, hA);
  }

  // partitionable split(key(42), 3): child i = threefry(key, (0, i))
  uint32_t k1a, k1b, k2a, k2b, k3a, k3b;
  threefry2x32(0u, 42u, 0u, 0u, &k1a, &k1b);
  threefry2x32(0u, 42u, 0u, 1u, &k2a, &k2b);
  threefry2x32(0u, 42u, 0u, 2u, &k3a, &k3b);
  G10 G1, G2, G3, G0;
  gumbel10_part(k1a, k1b, G1.g);
  gumbel10_part(k2a, k2b, G2.g);
  gumbel10_part(k3a, k3b, G3.g);
  memset(G0.g, 0, sizeof(G0.g));

  float* logz = out + 3;    // 130
  float* logy = out + 133;  // 128
  float* logx = out + 261;  // 128

  // stage 1: z  (K=1024, ny=16) — LNf inline in g1, no embeds
  k_head_g1<<<dim3(32, 16), 256, 0, stream>>>(hA, lnfg, c1emb, c2emb,
                                              nullptr, nullptr, G0, G0,
                                              h1w1, t1p, h1b3, logz, 130,
                                              nullptr, nullptr);
  k_head_g2<<<dim3(32, 16), 256, 0, stream>>>(t1p, 16, h1b1, h1w2, t2p);
  k_head_g3<<<16, 256, 0, stream>>>(t2p, h1b2, h1w3, logz, 130);

  // stage 2: y  (K=2048, ny=32) — z sampled in-kernel from logz
  k_head_g1<<<dim3(32, 32), 256, 0, stream>>>(hA, lnfg, c1emb, c2emb,
                                              logz, nullptr, G1, G0,
                                              h2w1, t1p, h2b3, logy, 128,
                                              out + 2, nullptr);
  k_head_g2<<<dim3(32, 16), 256, 0, stream>>>(t1p, 32, h2b1, h2w2, t2p);
  k_head_g3<<<16, 256, 0, stream>>>(t2p, h2b2, h2w3, logy, 128);

  // stage 3: x  (K=3072, ny=48) — z and y sampled in-kernel
  k_head_g1<<<dim3(32, 48), 256, 0, stream>>>(hA, lnfg, c1emb, c2emb,
                                              logz, logy, G1, G2,
                                              h3w1, t1p, h3b3, logx, 128,
                                              nullptr, out + 1);
  k_head_g2<<<dim3(32, 16), 256, 0, stream>>>(t1p, 48, h3b1, h3w2, t2p);
  k_head_g3<<<16, 256, 0, stream>>>(t2p, h3b2, h3w3, logx, 128);
  k_sample_final<<<1, 256, 0, stream>>>(logx, out + 0, G3);
}

// Round 12
// 1137.229 us; speedup vs baseline: 1.1415x; 1.1415x over previous
//
#include <hip/hip_runtime.h>
#include <cstdint>
#include <cstring>
#include <cmath>

constexpr int kH    = 16;
constexpr int kL    = 24;
constexpr int kS    = 4096;
constexpr int kEOS  = 129;
constexpr float kSCALE = 0.125f;   // 1/sqrt(64)
constexpr int kNS   = 32;          // attention splits
constexpr int kTOK  = kS / kNS;    // 128 tokens per split

struct G10 { float g[10]; };

// ---------------- reduction helpers ----------------

__device__ __forceinline__ float wave_sum(float v) {
  v += __shfl_xor(v, 32, 64); v += __shfl_xor(v, 16, 64);
  v += __shfl_xor(v, 8, 64);  v += __shfl_xor(v, 4, 64);
  v += __shfl_xor(v, 2, 64);  v += __shfl_xor(v, 1, 64);
  return v;
}
__device__ __forceinline__ float wave_max(float v) {
  v = fmaxf(v, __shfl_xor(v, 32, 64)); v = fmaxf(v, __shfl_xor(v, 16, 64));
  v = fmaxf(v, __shfl_xor(v, 8, 64));  v = fmaxf(v, __shfl_xor(v, 4, 64));
  v = fmaxf(v, __shfl_xor(v, 2, 64));  v = fmaxf(v, __shfl_xor(v, 1, 64));
  return v;
}
__device__ __forceinline__ float block_sum4(float v, float* red) {
  v = wave_sum(v);
  if ((threadIdx.x & 63) == 0) red[threadIdx.x >> 6] = v;
  __syncthreads();
  float s = red[0] + red[1] + red[2] + red[3];
  __syncthreads();
  return s;
}
__device__ __forceinline__ float block_max4(float v, float* red) {
  v = wave_max(v);
  if ((threadIdx.x & 63) == 0) red[threadIdx.x >> 6] = v;
  __syncthreads();
  float s = fmaxf(fmaxf(red[0], red[1]), fmaxf(red[2], red[3]));
  __syncthreads();
  return s;
}

__device__ __forceinline__ void ln_stats(const float* __restrict__ h, float* red,
                                         float& mean, float& rs) {
  int tid = threadIdx.x;
  float v0 = h[tid], v1 = h[tid + 256], v2 = h[tid + 512], v3 = h[tid + 768];
  float s = block_sum4(v0 + v1 + v2 + v3, red);
  mean = s * (1.0f / 1024.0f);
  float d0 = v0 - mean, d1 = v1 - mean, d2 = v2 - mean, d3 = v3 - mean;
  float sq = block_sum4(d0 * d0 + d1 * d1 + d2 * d2 + d3 * d3, red);
  rs = 1.0f / sqrtf(sq * (1.0f / 1024.0f) + 1e-5f);
}

__device__ __forceinline__ float gelu_f(float x) {
  float t = tanhf(0.7978845608028654f * (x + 0.044715f * x * x * x));
  return 0.5f * x * (1.0f + t);
}

// wave-parallel top-10 + gumbel sampler. Whole block must call (internal sync).
__device__ int wave_sampler(const float* __restrict__ logits, int n3,
                            const float* __restrict__ gb, bool eosmode,
                            int* ish) {
  int tid = threadIdx.x;
  if (tid < 64) {
    float a0 = (tid < n3) ? logits[tid] : -1e30f;
    float a1 = (tid + 64 < n3) ? logits[tid + 64] : -1e30f;
    float a2 = (tid + 128 < n3) ? logits[tid + 128] : -1e30f;
    float m = wave_max(fmaxf(a0, fmaxf(a1, a2)));
    float p0 = expf(a0 - m), p1 = expf(a1 - m), p2 = expf(a2 - m);
    float s = wave_sum(p0 + p1 + p2);
    p0 = p0 / s; p1 = p1 / s; p2 = p2 / s;
    float tp[10]; int ti[10];
    #pragma unroll
    for (int k = 0; k < 10; ++k) {
      float bv = p0; int bi = tid;
      if (p1 > bv) { bv = p1; bi = tid + 64; }
      if (p2 > bv) { bv = p2; bi = tid + 128; }
      #pragma unroll
      for (int off = 32; off > 0; off >>= 1) {
        float ov = __shfl_xor(bv, off, 64);
        int   oi = __shfl_xor(bi, off, 64);
        if (ov > bv || (ov == bv && oi < bi)) { bv = ov; bi = oi; }
      }
      tp[k] = bv; ti[k] = bi;
      if (bi == tid) p0 = -2.f;
      else if (bi == tid + 64) p1 = -2.f;
      else if (bi == tid + 128) p2 = -2.f;
    }
    if (tid == 0) {
      int choice;
      if (eosmode) {
        int is_eos = (ti[0] == kEOS);
        float mp[10]; float msum = 0.f;
        for (int k = 0; k < 10; ++k) {
          mp[k] = tp[k] * ((ti[k] != kEOS) ? 1.f : 0.f);
          msum += mp[k];
        }
        float bestsc = -1e30f; int ba = 0;
        for (int k = 0; k < 10; ++k) {
          float sc = logf(mp[k] / msum + 1e-9f) + gb[k];
          if (sc > bestsc) { bestsc = sc; ba = k; }
        }
        choice = is_eos ? kEOS : ti[ba];
      } else {
        float bestsc = -1e30f; int ba = 0;
        for (int k = 0; k < 10; ++k) {
          float sc = logf(tp[k] + 1e-9f) + gb[k];
          if (sc > bestsc) { bestsc = sc; ba = k; }
        }
        choice = ti[ba];
      }
      *ish = choice;
    }
  }
  __syncthreads();
  return *ish;
}

// ---------------- layer kernels ----------------

// A: fused LN1 + QKV gemv -> qkv_part[16][3072]; grid (48,16), 16-quad cols.
__global__ __launch_bounds__(256) void k_ln_qkv(const float* __restrict__ h,
                                                const float* __restrict__ g,
                                                const float* __restrict__ Wq,
                                                const float* __restrict__ Wk,
                                                const float* __restrict__ Wv,
                                                float* __restrict__ qkv_part,
                                                float* __restrict__ hres) {
  __shared__ float red4[4];
  __shared__ float xs[64];
  __shared__ float4 sh4[256];
  int tid = threadIdx.x;
  float mean, rs;
  ln_stats(h, red4, mean, rs);
  int by = blockIdx.y, rb = by * 64;
  if (tid < 64) xs[tid] = (h[rb + tid] - mean) * rs * g[rb + tid];
  if (blockIdx.x == 0 && tid < 64) hres[rb + tid] = h[rb + tid];
  __syncthreads();
  int c4 = tid & 15, w = tid >> 4;
  int vcol4 = blockIdx.x * 16 + c4;          // 0..767 (3072 cols)
  int mat = vcol4 >> 8;
  const float* W = (mat == 0) ? Wq : ((mat == 1) ? Wk : Wv);
  const float4* W4 = reinterpret_cast<const float4*>(W);
  int wcol4 = vcol4 & 255;
  float4 acc = {0.f, 0.f, 0.f, 0.f};
  int r0 = w * 4;
  #pragma unroll
  for (int i = 0; i < 4; ++i) {
    int j = r0 + i;
    float xv = xs[j];
    float4 wv = W4[(size_t)(rb + j) * 256 + wcol4];
    acc.x += xv * wv.x; acc.y += xv * wv.y; acc.z += xv * wv.z; acc.w += xv * wv.w;
  }
  sh4[tid] = acc;
  __syncthreads();
  if (tid < 16) {
    float4 a = sh4[tid];
    #pragma unroll
    for (int k = 1; k < 16; ++k) {
      float4 b = sh4[k * 16 + tid];
      a.x += b.x; a.y += b.y; a.z += b.z; a.w += b.w;
    }
    reinterpret_cast<float4*>(qkv_part)[(size_t)by * 768 + blockIdx.x * 16 + tid] = a;
  }
}

// B: attention partials. grid (kNS, kH). V prefetched to registers before
//    softmax so its HBM latency hides under max/exp/sum.
//    part entry stride 68: [m, l, -, -, o[64]]
__global__ __launch_bounds__(256) void k_attn(const float* __restrict__ qkv_part,
                                              const float* __restrict__ Kc,
                                              const float* __restrict__ Vc,
                                              float* __restrict__ part) {
  __shared__ float4 q4[16];
  __shared__ float4 kn4[16];
  __shared__ float4 vn4[16];
  __shared__ float sc[132];
  __shared__ float red4[4];
  __shared__ float4 ored[16][17];
  int split = blockIdx.x, head = blockIdx.y;
  int tid = threadIdx.x;
  if (tid < 64) {
    float s = 0.f;
    #pragma unroll
    for (int p = 0; p < 16; ++p) s += qkv_part[p * 3072 + head * 64 + tid];
    ((float*)q4)[tid] = s;
  } else if (tid < 128) {
    int d = tid - 64; float s = 0.f;
    #pragma unroll
    for (int p = 0; p < 16; ++p) s += qkv_part[p * 3072 + 1024 + head * 64 + d];
    ((float*)kn4)[d] = s;
  } else if (tid < 192) {
    int d = tid - 128; float s = 0.f;
    #pragma unroll
    for (int p = 0; p < 16; ++p) s += qkv_part[p * 3072 + 2048 + head * 64 + d];
    ((float*)vn4)[d] = s;
  }
  __syncthreads();
  int base = split * kTOK;
  bool last = (split == kNS - 1);
  int count = kTOK + (last ? 1 : 0);
  int wv = tid >> 6, lane = tid & 63, grp = lane >> 4, l16 = lane & 15;
  int g0 = wv * 4 + grp;
  float4 qf = q4[l16];
  const float4* K4 = reinterpret_cast<const float4*>(Kc);
  const float4* V4 = reinterpret_cast<const float4*>(Vc);
  #pragma unroll
  for (int i = 0; i < 8; ++i) {
    int t = g0 + 16 * i;
    float4 kf = K4[(size_t)(base + t) * 256 + head * 16 + l16];
    float d = qf.x * kf.x + qf.y * kf.y + qf.z * kf.z + qf.w * kf.w;
    d += __shfl_xor(d, 1, 16); d += __shfl_xor(d, 2, 16);
    d += __shfl_xor(d, 4, 16); d += __shfl_xor(d, 8, 16);
    if (l16 == 0) sc[t] = d * kSCALE;
  }
  if (last && g0 == 0) {
    float4 kf = kn4[l16];
    float d = qf.x * kf.x + qf.y * kf.y + qf.z * kf.z + qf.w * kf.w;
    d += __shfl_xor(d, 1, 16); d += __shfl_xor(d, 2, 16);
    d += __shfl_xor(d, 4, 16); d += __shfl_xor(d, 8, 16);
    if (l16 == 0) sc[128] = d * kSCALE;
  }
  // V prefetch into registers — in flight across the softmax barriers
  float4 vreg[8];
  #pragma unroll
  for (int i = 0; i < 8; ++i) {
    int t = g0 + 16 * i;
    vreg[i] = V4[(size_t)(base + t) * 256 + head * 16 + l16];
  }
  __syncthreads();
  float v = (tid < count) ? sc[tid] : -1e30f;
  float m = block_max4(v, red4);
  float pexp = 0.f;
  if (tid < count) { pexp = expf(sc[tid] - m); sc[tid] = pexp; }
  float l = block_sum4(pexp, red4);
  float4 acc = {0.f, 0.f, 0.f, 0.f};
  #pragma unroll
  for (int i = 0; i < 8; ++i) {
    int t = g0 + 16 * i;
    float p = sc[t];
    acc.x += p * vreg[i].x; acc.y += p * vreg[i].y;
    acc.z += p * vreg[i].z; acc.w += p * vreg[i].w;
  }
  if (last && g0 == 0) {
    float p = sc[128];
    float4 vf = vn4[l16];
    acc.x += p * vf.x; acc.y += p * vf.y; acc.z += p * vf.z; acc.w += p * vf.w;
  }
  ored[g0][l16] = acc;
  __syncthreads();
  float* pp = &part[(size_t)(head * kNS + split) * 68];
  if (tid < 16) {
    float4 s = ored[0][tid];
    #pragma unroll
    for (int k = 1; k < 16; ++k) {
      float4 b = ored[k][tid];
      s.x += b.x; s.y += b.y; s.z += b.z; s.w += b.w;
    }
    reinterpret_cast<float4*>(pp + 4)[tid] = s;
  }
  if (tid == 0) { pp[0] = m; pp[1] = l; }
}

// C: combine 32 splits per head + Wo gemv (16-quad colblocks, grid (16,16))
__global__ __launch_bounds__(256) void k_comb_wo(const float* __restrict__ part,
                                                 const float* __restrict__ Wo,
                                                 float* __restrict__ hout) {
  __shared__ float o[64];
  __shared__ float4 sh4[256];
  int tid = threadIdx.x;
  int head = blockIdx.y, bx = blockIdx.x;
  if (tid < 64) {
    const float* pp = part + (size_t)(head * kNS) * 68;
    float m = -1e30f;
    for (int s = 0; s < kNS; ++s) m = fmaxf(m, pp[s * 68]);
    float l = 0.f, acc = 0.f;
    for (int s = 0; s < kNS; ++s) {
      float e = expf(pp[s * 68] - m);
      l += e * pp[s * 68 + 1];
      acc += e * pp[s * 68 + 4 + tid];
    }
    o[tid] = acc / l;
  }
  __syncthreads();
  int c4 = tid & 15, w = tid >> 4;
  int vcol4 = bx * 16 + c4;
  const float4* W4 = reinterpret_cast<const float4*>(Wo);
  float4 acc = {0.f, 0.f, 0.f, 0.f};
  int r0 = w * 4;
  #pragma unroll
  for (int i = 0; i < 4; ++i) {
    int r = r0 + i;
    float xv = o[r];
    float4 wv = W4[(size_t)(head * 64 + r) * 256 + vcol4];
    acc.x += xv * wv.x; acc.y += xv * wv.y; acc.z += xv * wv.z; acc.w += xv * wv.w;
  }
  sh4[tid] = acc;
  __syncthreads();
  if (tid < 16) {
    float4 a = sh4[tid];
    #pragma unroll
    for (int k = 1; k < 16; ++k) {
      float4 b = sh4[k * 16 + tid];
      a.x += b.x; a.y += b.y; a.z += b.z; a.w += b.w;
    }
    int vcol = (bx * 16 + tid) * 4;
    atomicAdd(&hout[vcol],     a.x);
    atomicAdd(&hout[vcol + 1], a.y);
    atomicAdd(&hout[vcol + 2], a.z);
    atomicAdd(&hout[vcol + 3], a.w);
  }
}

// D: fused LN2 + [Wg|Wu] gemv -> gu_part[16][8192]; bx==0 copies h -> hres
__global__ __launch_bounds__(256) void k_ln_gu(const float* __restrict__ h,
                                               const float* __restrict__ g,
                                               const float* __restrict__ Wg,
                                               const float* __restrict__ Wu,
                                               float* __restrict__ gu_part,
                                               float* __restrict__ hres) {
  __shared__ float red4[4];
  __shared__ float xs[64];
  __shared__ float4 sh4[256];
  int tid = threadIdx.x;
  float mean, rs;
  ln_stats(h, red4, mean, rs);
  int by = blockIdx.y, rb = by * 64;
  if (tid < 64) xs[tid] = (h[rb + tid] - mean) * rs * g[rb + tid];
  if (blockIdx.x == 0 && tid < 64) hres[rb + tid] = h[rb + tid];
  __syncthreads();
  int c4 = tid & 63, w = tid >> 6;
  int vcol4 = blockIdx.x * 64 + c4;          // 0..2047 (8192 cols)
  int mat = vcol4 >> 10;
  const float4* W4 = reinterpret_cast<const float4*>(mat ? Wu : Wg);
  int wcol4 = vcol4 & 1023;
  float4 acc = {0.f, 0.f, 0.f, 0.f};
  int r0 = w * 16;
  #pragma unroll
  for (int i = 0; i < 16; ++i) {
    int j = r0 + i;
    float xv = xs[j];
    float4 wv = W4[(size_t)(rb + j) * 1024 + wcol4];
    acc.x += xv * wv.x; acc.y += xv * wv.y; acc.z += xv * wv.z; acc.w += xv * wv.w;
  }
  sh4[tid] = acc;
  __syncthreads();
  if (tid < 64) {
    float4 a = sh4[tid], b = sh4[tid + 64], c = sh4[tid + 128], d = sh4[tid + 192];
    a.x += b.x + c.x + d.x; a.y += b.y + c.y + d.y;
    a.z += b.z + c.z + d.z; a.w += b.w + c.w + d.w;
    reinterpret_cast<float4*>(gu_part)[(size_t)by * 2048 + blockIdx.x * 64 + tid] = a;
  }
}

// E: act = gelu(sum g)*sum u, then act @ Wd, atomicAdd into hout (pre-loaded with h)
__global__ __launch_bounds__(256) void k_act_wd(const float* __restrict__ gu_part,
                                                const float* __restrict__ Wd,
                                                float* __restrict__ hout) {
  __shared__ float xs[64];
  __shared__ float4 sh4[256];
  int tid = threadIdx.x;
  int by = blockIdx.y, rb = by * 64;
  if (tid < 64) {
    float gs = 0.f, us = 0.f;
    #pragma unroll
    for (int p = 0; p < 16; ++p) {
      gs += gu_part[p * 8192 + rb + tid];
      us += gu_part[p * 8192 + 4096 + rb + tid];
    }
    xs[tid] = gelu_f(gs) * us;
  }
  __syncthreads();
  int c4 = tid & 63, w = tid >> 6;
  int vcol4 = blockIdx.x * 64 + c4;          // 0..255
  const float4* W4 = reinterpret_cast<const float4*>(Wd);
  float4 acc = {0.f, 0.f, 0.f, 0.f};
  int r0 = w * 16;
  #pragma unroll
  for (int i = 0; i < 16; ++i) {
    int j = r0 + i;
    float xv = xs[j];
    float4 wv = W4[(size_t)(rb + j) * 256 + vcol4];
    acc.x += xv * wv.x; acc.y += xv * wv.y; acc.z += xv * wv.z; acc.w += xv * wv.w;
  }
  sh4[tid] = acc;
  __syncthreads();
  if (tid < 64) {
    float4 a = sh4[tid], b = sh4[tid + 64], c = sh4[tid + 128], d = sh4[tid + 192];
    a.x += b.x + c.x + d.x; a.y += b.y + c.y + d.y;
    a.z += b.z + c.z + d.z; a.w += b.w + c.w + d.w;
    int vcol = (blockIdx.x * 64 + tid) * 4;
    atomicAdd(&hout[vcol],     a.x);
    atomicAdd(&hout[vcol + 1], a.y);
    atomicAdd(&hout[vcol + 2], a.z);
    atomicAdd(&hout[vcol + 3], a.w);
  }
}

// ---------------- head kernels ----------------

// g1: 16-quad colblocks, grid (16, ny). Rows r<1024 use inline LNf(hA);
//     rows in [1024,2048) gather c1emb[z]; rows >=2048 gather c2emb[y].
//     z / y are re-derived locally via the wave sampler (deterministic).
//     (0,0) block inits logits = b3; designated blocks write out z / y.
__global__ __launch_bounds__(256) void k_head_g1(const float* __restrict__ hA,
                                                 const float* __restrict__ lnfg,
                                                 const float* __restrict__ c1emb,
                                                 const float* __restrict__ c2emb,
                                                 const float* __restrict__ zlogits,
                                                 const float* __restrict__ ylogits,
                                                 G10 Gz, G10 Gy,
                                                 const float* __restrict__ W,
                                                 float* __restrict__ t1_part,
                                                 const float* __restrict__ b3,
                                                 float* __restrict__ logits, int n3,
                                                 float* __restrict__ outz,
                                                 float* __restrict__ outy) {
  __shared__ float red4[4];
  __shared__ float xs[64];
  __shared__ float4 sh4[256];
  __shared__ int ish;
  int tid = threadIdx.x;
  int by = blockIdx.y, rb = by * 64;
  int zv = 0, yv = 0;
  if (by >= 16 && by < 32) {
    zv = wave_sampler(zlogits, 130, Gz.g, true, &ish);
    if (outz && blockIdx.x == 0 && by == 16 && tid == 0) *outz = (float)zv;
  } else if (by >= 32) {
    yv = wave_sampler(ylogits, 128, Gy.g, false, &ish);
    if (outy && blockIdx.x == 0 && by == 32 && tid == 0) *outy = (float)yv;
  }
  float mean, rs;
  ln_stats(hA, red4, mean, rs);
  if (blockIdx.x == 0 && by == 0 && tid < n3) logits[tid] = b3[tid];
  if (tid < 64) {
    int r = rb + tid;
    if (r < 1024) {
      xs[tid] = (hA[r] - mean) * rs * lnfg[r];
    } else if (r < 2048) {
      int zi = zv > 127 ? 127 : zv;
      xs[tid] = c1emb[(size_t)zi * 1024 + (r - 1024)];
    } else {
      xs[tid] = c2emb[(size_t)yv * 1024 + (r - 2048)];
    }
  }
  __syncthreads();
  int c4 = tid & 15, w = tid >> 4;
  int vcol4 = blockIdx.x * 16 + c4;
  const float4* W4 = reinterpret_cast<const float4*>(W);
  float4 acc = {0.f, 0.f, 0.f, 0.f};
  int r0 = w * 4;
  #pragma unroll
  for (int i = 0; i < 4; ++i) {
    float xv = xs[r0 + i];
    float4 wv = W4[(size_t)(rb + r0 + i) * 256 + vcol4];
    acc.x += xv * wv.x; acc.y += xv * wv.y; acc.z += xv * wv.z; acc.w += xv * wv.w;
  }
  sh4[tid] = acc;
  __syncthreads();
  if (tid < 16) {
    float4 a = sh4[tid];
    #pragma unroll
    for (int k = 1; k < 16; ++k) {
      float4 b = sh4[k * 16 + tid];
      a.x += b.x; a.y += b.y; a.z += b.z; a.w += b.w;
    }
    reinterpret_cast<float4*>(t1_part)[(size_t)by * 256 + blockIdx.x * 16 + tid] = a;
  }
}

// g2: relu(b1 + sum_ny t1_part) @ W; 16-quad colblocks, grid (16, 16)
__global__ __launch_bounds__(256) void k_head_g2(const float* __restrict__ t1_part,
                                                 int ny,
                                                 const float* __restrict__ b1,
                                                 const float* __restrict__ W,
                                                 float* __restrict__ t2_part) {
  __shared__ float xs[64];
  __shared__ float4 sh4[256];
  int tid = threadIdx.x;
  int by = blockIdx.y, rb = by * 64;
  if (tid < 64) {
    float s = b1[rb + tid];
    for (int p = 0; p < ny; ++p) s += t1_part[p * 1024 + rb + tid];
    xs[tid] = fmaxf(s, 0.f);
  }
  __syncthreads();
  int c4 = tid & 15, w = tid >> 4;
  int vcol4 = blockIdx.x * 16 + c4;
  const float4* W4 = reinterpret_cast<const float4*>(W);
  float4 acc = {0.f, 0.f, 0.f, 0.f};
  int r0 = w * 4;
  #pragma unroll
  for (int i = 0; i < 4; ++i) {
    float xv = xs[r0 + i];
    float4 wv = W4[(size_t)(rb + r0 + i) * 256 + vcol4];
    acc.x += xv * wv.x; acc.y += xv * wv.y; acc.z += xv * wv.z; acc.w += xv * wv.w;
  }
  sh4[tid] = acc;
  __syncthreads();
  if (tid < 16) {
    float4 a = sh4[tid];
    #pragma unroll
    for (int k = 1; k < 16; ++k) {
      float4 b = sh4[k * 16 + tid];
      a.x += b.x; a.y += b.y; a.z += b.z; a.w += b.w;
    }
    reinterpret_cast<float4*>(t2_part)[(size_t)by * 256 + blockIdx.x * 16 + tid] = a;
  }
}

// g3: relu(b2 + sum_16 t2_part) @ W (1024 x n3) -> atomicAdd logits
__global__ __launch_bounds__(256) void k_head_g3(const float* __restrict__ t2_part,
                                                 const float* __restrict__ b2,
                                                 const float* __restrict__ W,
                                                 float* __restrict__ logits, int n3) {
  __shared__ float xs[64];
  int tid = threadIdx.x;
  int rb = blockIdx.x * 64;
  if (tid < 64) {
    float s = b2[rb + tid];
    #pragma unroll
    for (int p = 0; p < 16; ++p) s += t2_part[p * 1024 + rb + tid];
    xs[tid] = fmaxf(s, 0.f);
  }
  __syncthreads();
  if (tid < n3) {
    float acc = 0.f;
    for (int i = 0; i < 64; ++i) acc += xs[i] * W[(size_t)(rb + i) * n3 + tid];
    atomicAdd(&logits[tid], acc);
  }
}

// final sampler (stage 3, x coordinate)
__global__ void k_sample_final(const float* __restrict__ logits,
                               float* __restrict__ outslot, G10 gb) {
  __shared__ int ish;
  int v = wave_sampler(logits, 128, gb.g, false, &ish);
  if (threadIdx.x == 0) *outslot = (float)v;
}

// ---------------- host: JAX threefry2x32 (partitionable) ----------------

static inline uint32_t rotl32(uint32_t x, uint32_t r) { return (x << r) | (x >> (32 - r)); }

static void threefry2x32(uint32_t k0, uint32_t k1, uint32_t x0, uint32_t x1,
                         uint32_t* o0, uint32_t* o1) {
  uint32_t ks0 = k0, ks1 = k1, ks2 = k0 ^ k1 ^ 0x1BD11BDAu;
  const uint32_t R0[4] = {13, 15, 26, 6};
  const uint32_t R1[4] = {17, 29, 16, 24};
  x0 += ks0; x1 += ks1;
  for (int j = 0; j < 4; ++j) { x0 += x1; x1 = rotl32(x1, R0[j]); x1 ^= x0; }
  x0 += ks1; x1 += ks2 + 1u;
  for (int j = 0; j < 4; ++j) { x0 += x1; x1 = rotl32(x1, R1[j]); x1 ^= x0; }
  x0 += ks2; x1 += ks0 + 2u;
  for (int j = 0; j < 4; ++j) { x0 += x1; x1 = rotl32(x1, R0[j]); x1 ^= x0; }
  x0 += ks0; x1 += ks1 + 3u;
  for (int j = 0; j < 4; ++j) { x0 += x1; x1 = rotl32(x1, R1[j]); x1 ^= x0; }
  x0 += ks1; x1 += ks2 + 4u;
  for (int j = 0; j < 4; ++j) { x0 += x1; x1 = rotl32(x1, R0[j]); x1 ^= x0; }
  x0 += ks2; x1 += ks0 + 5u;
  *o0 = x0; *o1 = x1;
}

static void gumbel10_part(uint32_t k0, uint32_t k1, float* g) {
  const float tiny = 1.1754943508222875e-38f;
  for (int i = 0; i < 10; ++i) {
    uint32_t a, c;
    threefry2x32(k0, k1, 0u, (uint32_t)i, &a, &c);
    uint32_t bits = a ^ c;
    uint32_t fb = (bits >> 9) | 0x3f800000u;
    float f; memcpy(&f, &fb, 4);
    f -= 1.0f;
    float u = f * (1.0f - tiny) + tiny;
    if (u < tiny) u = tiny;
    g[i] = -logf(-logf(u));
  }
}

// ---------------- entry ----------------

extern "C" void kernel_launch(void* const* d_in, const int* in_sizes, int n_in,
                              void* d_out, int out_size, void* d_ws, size_t ws_size,
                              hipStream_t stream) {
  (void)in_sizes; (void)n_in; (void)out_size; (void)ws_size;
  const float* x      = (const float*)d_in[0];
  const float* kcache = (const float*)d_in[1];
  const float* vcache = (const float*)d_in[2];
  const float* ln1g   = (const float*)d_in[3];
  const float* Wq     = (const float*)d_in[4];
  const float* Wk     = (const float*)d_in[5];
  const float* Wv     = (const float*)d_in[6];
  const float* Wo     = (const float*)d_in[7];
  const float* ln2g   = (const float*)d_in[8];
  const float* Wg     = (const float*)d_in[9];
  const float* Wu     = (const float*)d_in[10];
  const float* Wd     = (const float*)d_in[11];
  const float* lnfg   = (const float*)d_in[12];
  const float* h1w1 = (const float*)d_in[13]; const float* h1b1 = (const float*)d_in[14];
  const float* h1w2 = (const float*)d_in[15]; const float* h1b2 = (const float*)d_in[16];
  const float* h1w3 = (const float*)d_in[17]; const float* h1b3 = (const float*)d_in[18];
  const float* h2w1 = (const float*)d_in[19]; const float* h2b1 = (const float*)d_in[20];
  const float* h2w2 = (const float*)d_in[21]; const float* h2b2 = (const float*)d_in[22];
  const float* h2w3 = (const float*)d_in[23]; const float* h2b3 = (const float*)d_in[24];
  const float* h3w1 = (const float*)d_in[25]; const float* h3b1 = (const float*)d_in[26];
  const float* h3w2 = (const float*)d_in[27]; const float* h3b2 = (const float*)d_in[28];
  const float* h3w3 = (const float*)d_in[29]; const float* h3b3 = (const float*)d_in[30];
  const float* c1emb = (const float*)d_in[31];
  const float* c2emb = (const float*)d_in[32];

  float* ws = (float*)d_ws;
  float* hA   = ws;                  // 1024
  float* hB   = ws + 1024;           // 1024
  float* qkvp = ws + 2048;           // 16*3072 = 49152
  float* part = ws + 51200;          // 16*32*68 = 34816
  float* gup  = ws + 86016;          // 16*8192 = 131072
  float* t2p  = ws + 217088;         // 16*1024 = 16384
  float* t1p  = gup;                 // reuse (heads only): up to 48*1024
  float* out  = (float*)d_out;

  for (int l = 0; l < kL; ++l) {
    const float* Wq_l = Wq + (size_t)l * 1024 * 1024;
    const float* Wk_l = Wk + (size_t)l * 1024 * 1024;
    const float* Wv_l = Wv + (size_t)l * 1024 * 1024;
    const float* Wo_l = Wo + (size_t)l * 1024 * 1024;
    const float* Wg_l = Wg + (size_t)l * 1024 * 4096;
    const float* Wu_l = Wu + (size_t)l * 1024 * 4096;
    const float* Wd_l = Wd + (size_t)l * 4096 * 1024;
    const float* Kc_l = kcache + (size_t)l * kS * 1024;
    const float* Vc_l = vcache + (size_t)l * kS * 1024;
    const float* h_in = (l == 0) ? x : hA;

    // A: LN1 fused + QKV partials (768 blocks, 3/CU); copies h_in -> hB
    k_ln_qkv<<<dim3(48, 16), 256, 0, stream>>>(h_in, ln1g + (size_t)l * 1024,
                                               Wq_l, Wk_l, Wv_l, qkvp, hB);
    // B: attention partials over S+1 (V reg-prefetched)
    k_attn<<<dim3(kNS, kH), 256, 0, stream>>>(qkvp, Kc_l, Vc_l, part);
    // C: combine + Wo, hB += o @ Wo (256 blocks)
    k_comb_wo<<<dim3(16, kH), 256, 0, stream>>>(part, Wo_l, hB);
    // D: LN2 fused + [Wg|Wu] partials; copies hB -> hA (residual base)
    k_ln_gu<<<dim3(32, 16), 256, 0, stream>>>(hB, ln2g + (size_t)l * 1024,
                                              Wg_l, Wu_l, gup, hA);
    // E: hA += (gelu(g)*u) @ Wd
    k_act_wd<<<dim3(4, 64), 256, 0, stream>>>(gup, Wd_l, hA);
  }

  // partitionable split(key(42), 3): child i = threefry(key, (0, i))
  uint32_t k1a, k1b, k2a, k2b, k3a, k3b;
  threefry2x32(0u, 42u, 0u, 0u, &k1a, &k1b);
  threefry2x32(0u, 42u, 0u, 1u, &k2a, &k2b);
  threefry2x32(0u, 42u, 0u, 2u, &k3a, &k3b);
  G10 G1, G2, G3, G0;
  gumbel10_part(k1a, k1b, G1.g);
  gumbel10_part(k2a, k2b, G2.g);
  gumbel10_part(k3a, k3b, G3.g);
  memset(G0.g, 0, sizeof(G0.g));

  float* logz = out + 3;    // 130
  float* logy = out + 133;  // 128
  float* logx = out + 261;  // 128

  // stage 1: z  (K=1024, ny=16) — LNf inline in g1, no embeds
  k_head_g1<<<dim3(16, 16), 256, 0, stream>>>(hA, lnfg, c1emb, c2emb,
                                              nullptr, nullptr, G0, G0,
                                              h1w1, t1p, h1b3, logz, 130,
                                              nullptr, nullptr);
  k_head_g2<<<dim3(16, 16), 256, 0, stream>>>(t1p, 16, h1b1, h1w2, t2p);
  k_head_g3<<<16, 256, 0, stream>>>(t2p, h1b2, h1w3, logz, 130);

  // stage 2: y  (K=2048, ny=32) — z sampled in-kernel from logz
  k_head_g1<<<dim3(16, 32), 256, 0, stream>>>(hA, lnfg, c1emb, c2emb,
                                              logz, nullptr, G1, G0,
                                              h2w1, t1p, h2b3, logy, 128,
                                              out + 2, nullptr);
  k_head_g2<<<dim3(16, 16), 256, 0, stream>>>(t1p, 32, h2b1, h2w2, t2p);
  k_head_g3<<<16, 256, 0, stream>>>(t2p, h2b2, h2w3, logy, 128);

  // stage 3: x  (K=3072, ny=48) — z and y sampled in-kernel
  k_head_g1<<<dim3(16, 48), 256, 0, stream>>>(hA, lnfg, c1emb, c2emb,
                                              logz, logy, G1, G2,
                                              h3w1, t1p, h3b3, logx, 128,
                                              nullptr, out + 1);
  k_head_g2<<<dim3(16, 16), 256, 0, stream>>>(t1p, 48, h3b1, h3w2, t2p);
  k_head_g3<<<16, 256, 0, stream>>>(t2p, h3b2, h3w3, logx, 128);
  k_sample_final<<<1, 256, 0, stream>>>(logx, out + 0, G3);
}